// Round 1
// baseline (1544.647 us; speedup 1.0000x reference)
//
#include <hip/hip_runtime.h>

#define H 224
#define W 224
#define HW (H*W)
#define BATCH 2
#define CIN 64
#define COUT 64
#define NOFF 18   // 2*9 offset channels

// ---------------------------------------------------------------------------
// Offset conv: 3x3, pad 1. x (B,64,H,W) * w (18,64,3,3) + bias -> off (B,18,H,W)
// One thread per pixel, all 18 output channels. Weight index is wave-uniform
// -> compiler should select s_load (scalar operand into v_fmac).
// ---------------------------------------------------------------------------
__global__ __launch_bounds__(256) void k_offconv(const float* __restrict__ x,
                                                 const float* __restrict__ w,
                                                 const float* __restrict__ bias,
                                                 float* __restrict__ off) {
    int pid = blockIdx.x * 256 + threadIdx.x;     // grid exactly B*HW/256
    int b  = pid / HW;
    int ij = pid % HW;
    int i  = ij / W;
    int j  = ij % W;

    float acc[NOFF];
#pragma unroll
    for (int o = 0; o < NOFF; ++o) acc[o] = bias[o];

    const float* xb = x + b * CIN * HW;
    for (int c = 0; c < CIN; ++c) {
        const float* xc = xb + c * HW;
        float v[9];
#pragma unroll
        for (int u = 0; u < 3; ++u) {
#pragma unroll
            for (int t = 0; t < 3; ++t) {
                int ii = i + u - 1, jj = j + t - 1;
                bool ok = (ii >= 0) & (ii < H) & (jj >= 0) & (jj < W);
                v[u * 3 + t] = ok ? xc[ii * W + jj] : 0.0f;
            }
        }
#pragma unroll
        for (int o = 0; o < NOFF; ++o) {
            float a = acc[o];
#pragma unroll
            for (int k = 0; k < 9; ++k)
                a += w[(o * CIN + c) * 9 + k] * v[k];
            acc[o] = a;
        }
    }
#pragma unroll
    for (int o = 0; o < NOFF; ++o)
        off[(b * NOFF + o) * HW + ij] = acc[o];
}

// ---------------------------------------------------------------------------
// Fused deformable sampling + (ks,stride-ks) conv collapsed to a K=576 dot.
// One thread per pixel: 9 sample points (shared across channels), then
// for each input channel gather 4 corners x 9 points, bilinear combine,
// and accumulate into 64 output channels. Weights (64,64,9) read with
// uniform indices -> SGPR operands.
// ---------------------------------------------------------------------------
__global__ __launch_bounds__(256) void k_deform(const float* __restrict__ x,
                                                const float* __restrict__ off,
                                                const float* __restrict__ w,
                                                float* __restrict__ out) {
    int pid = blockIdx.x * 256 + threadIdx.x;
    int b  = pid / HW;
    int ij = pid % HW;
    int i  = ij / W;
    int j  = ij % W;

    const float* offb = off + b * NOFF * HW + ij;

    float g0[9], g1[9], g2[9], g3[9];
    int   i0[9], i1[9], i2[9], i3[9];

#pragma unroll
    for (int n = 0; n < 9; ++n) {
        int k1 = n / 3, k2 = n % 3;
        // p = p0 + pn + offset = (i+1) + (k1-1) + off_x  (exact int arith)
        float px_f = (float)(i + k1) + offb[n * HW];
        float py_f = (float)(j + k2) + offb[(9 + n) * HW];
        float qx = floorf(px_f), qy = floorf(py_f);
        int ltx = min(max((int)qx, 0), H - 1);
        int lty = min(max((int)qy, 0), W - 1);
        int rbx = min(max((int)qx + 1, 0), H - 1);
        int rby = min(max((int)qy + 1, 0), W - 1);
        float px = fminf(fmaxf(px_f, 0.0f), (float)(H - 1));
        float py = fminf(fmaxf(py_f, 0.0f), (float)(W - 1));
        float alt = 1.0f + ((float)ltx - px);
        float arb = 1.0f - ((float)rbx - px);
        float blt = 1.0f + ((float)lty - py);
        float brb = 1.0f - ((float)rby - py);
        g0[n] = alt * blt;  i0[n] = ltx * W + lty;   // lt
        g1[n] = arb * brb;  i1[n] = rbx * W + rby;   // rb
        g2[n] = alt * brb;  i2[n] = ltx * W + rby;   // lb
        g3[n] = arb * blt;  i3[n] = rbx * W + lty;   // rt
    }

    float acc[COUT];
#pragma unroll
    for (int o = 0; o < COUT; ++o) acc[o] = 0.0f;

    const float* xb = x + b * CIN * HW;
    for (int c = 0; c < CIN; ++c) {
        const float* xc = xb + c * HW;
        float xo[9];
#pragma unroll
        for (int n = 0; n < 9; ++n) {
            xo[n] = g0[n] * xc[i0[n]] + g1[n] * xc[i1[n]]
                  + g2[n] * xc[i2[n]] + g3[n] * xc[i3[n]];
        }
        const float* wc = w + c * 9;
#pragma unroll
        for (int o = 0; o < COUT; ++o) {
            float a = acc[o];
#pragma unroll
            for (int n = 0; n < 9; ++n)
                a += wc[o * CIN * 9 + n] * xo[n];
            acc[o] = a;
        }
    }
#pragma unroll
    for (int o = 0; o < COUT; ++o)
        out[(b * COUT + o) * HW + ij] = acc[o];
}

// ---------------------------------------------------------------------------
// Per-channel sum / sumsq. grid = 64 channels * 4 splits. stats[0..63]=sum,
// stats[64..127]=sumsq (must be zeroed beforehand).
// ---------------------------------------------------------------------------
__global__ __launch_bounds__(256) void k_stats(const float* __restrict__ y,
                                               float* __restrict__ stats) {
    int c = blockIdx.x >> 2;
    int s = blockIdx.x & 3;
    const int seg = HW / 4;   // 12544
    float sum = 0.0f, sq = 0.0f;
    for (int b = 0; b < BATCH; ++b) {
        const float* p = y + (b * COUT + c) * HW + s * seg;
        for (int t = threadIdx.x; t < seg; t += 256) {
            float v = p[t];
            sum += v;
            sq  += v * v;
        }
    }
    // wave reduce
#pragma unroll
    for (int d = 32; d > 0; d >>= 1) {
        sum += __shfl_down(sum, d, 64);
        sq  += __shfl_down(sq,  d, 64);
    }
    __shared__ float red[8];   // 4 waves * 2
    int wave = threadIdx.x >> 6;
    if ((threadIdx.x & 63) == 0) { red[wave] = sum; red[4 + wave] = sq; }
    __syncthreads();
    if (threadIdx.x == 0) {
        float ts = red[0] + red[1] + red[2] + red[3];
        float tq = red[4] + red[5] + red[6] + red[7];
        atomicAdd(&stats[c], ts);
        atomicAdd(&stats[COUT + c], tq);
    }
}

// ---------------------------------------------------------------------------
// Apply BN (biased var) + ReLU.
// ---------------------------------------------------------------------------
__global__ __launch_bounds__(256) void k_bnrelu(const float* __restrict__ y,
                                                const float* __restrict__ stats,
                                                const float* __restrict__ gamma,
                                                const float* __restrict__ beta,
                                                float* __restrict__ out) {
    int t = blockIdx.x * 256 + threadIdx.x;      // grid = B*COUT*HW/256
    int c = (t / HW) % COUT;
    const float inv_m = 1.0f / (float)(BATCH * HW);
    float mu  = stats[c] * inv_m;
    float var = stats[COUT + c] * inv_m - mu * mu;
    float r   = rsqrtf(var + 1e-5f);
    float val = (y[t] - mu) * r * gamma[c] + beta[c];
    out[t] = fmaxf(val, 0.0f);
}

// ---------------------------------------------------------------------------
extern "C" void kernel_launch(void* const* d_in, const int* in_sizes, int n_in,
                              void* d_out, int out_size, void* d_ws, size_t ws_size,
                              hipStream_t stream) {
    const float* x       = (const float*)d_in[0];
    const float* w_off1  = (const float*)d_in[1];
    const float* b_off1  = (const float*)d_in[2];
    const float* w_conv1 = (const float*)d_in[3];
    const float* gamma1  = (const float*)d_in[4];
    const float* beta1   = (const float*)d_in[5];
    const float* w_off2  = (const float*)d_in[6];
    const float* b_off2  = (const float*)d_in[7];
    const float* w_conv2 = (const float*)d_in[8];
    const float* gamma2  = (const float*)d_in[9];
    const float* beta2   = (const float*)d_in[10];
    float* out = (float*)d_out;

    float* ws    = (float*)d_ws;
    float* off   = ws;                                   // B*18*HW
    float* yraw  = off  + (size_t)BATCH * NOFF * HW;     // B*64*HW
    float* y1    = yraw + (size_t)BATCH * COUT * HW;     // B*64*HW
    float* stats = y1   + (size_t)BATCH * COUT * HW;     // 128

    const int pix_blocks = (BATCH * HW) / 256;           // 392
    const int el_blocks  = (BATCH * COUT * HW) / 256;    // 25088

    // ---- stage 1 ----
    k_offconv<<<pix_blocks, 256, 0, stream>>>(x, w_off1, b_off1, off);
    k_deform <<<pix_blocks, 256, 0, stream>>>(x, off, w_conv1, yraw);
    hipMemsetAsync(stats, 0, 2 * COUT * sizeof(float), stream);
    k_stats  <<<COUT * 4, 256, 0, stream>>>(yraw, stats);
    k_bnrelu <<<el_blocks, 256, 0, stream>>>(yraw, stats, gamma1, beta1, y1);

    // ---- stage 2 ----
    k_offconv<<<pix_blocks, 256, 0, stream>>>(y1, w_off2, b_off2, off);
    k_deform <<<pix_blocks, 256, 0, stream>>>(y1, off, w_conv2, yraw);
    hipMemsetAsync(stats, 0, 2 * COUT * sizeof(float), stream);
    k_stats  <<<COUT * 4, 256, 0, stream>>>(yraw, stats);
    k_bnrelu <<<el_blocks, 256, 0, stream>>>(yraw, stats, gamma2, beta2, out);
}